// Round 11
// baseline (1879.012 us; speedup 1.0000x reference)
//
#include <hip/hip_runtime.h>

typedef _Float16 f16;
typedef _Float16 f16x8 __attribute__((ext_vector_type(8)));
typedef _Float16 f16x4 __attribute__((ext_vector_type(4)));
typedef float    f32x4 __attribute__((ext_vector_type(4)));

#define B_SZ   2048
#define NCH    256
#define L0_    127
#define L1_    125
#define L2_    123
#define L3_    121
#define F1_    512
#define FCK    30976
#define KCH    968         // 30976 / 32 k-chunks
#define SPLIT  31          // split-K for FC1
#define KPS    32          // ceil(968/31)

// async global->LDS, 16B per lane; dest = wave-uniform base + lane*16
__device__ __forceinline__ void gl16(const f16* g, f16* l) {
    __builtin_amdgcn_global_load_lds(
        (const __attribute__((address_space(1))) void*)g,
        (__attribute__((address_space(3))) void*)l, 16, 0, 0);
}

// ---------------------------------------------------------------------------
// preps: weights chunk-major [ks][co][32k]; Wf1 chunk-major over kt=l*256+co
// ---------------------------------------------------------------------------
__global__ __launch_bounds__(256) void prep_wpw(const float* __restrict__ Wp,
                                                f16* __restrict__ wpw) {
    int idx = blockIdx.x * 256 + threadIdx.x;
    if (idx >= NCH * 128) return;
    int ks = idx >> 13, rem = idx & 8191;
    int co = rem >> 5, w5 = rem & 31;
    int j = ((ks & 3) << 5) + w5;            // ci 0..127
    float v = (j < 64) ? Wp[co * 128 + j * 2 + 1] : Wp[co * 128 + (j - 64) * 2];
    wpw[idx] = (f16)v;
}

__global__ __launch_bounds__(256) void prep_wct(const float* __restrict__ W,
                                                f16* __restrict__ wct) {
    int idx = blockIdx.x * 256 + threadIdx.x;
    if (idx >= NCH * 768) return;
    int ks = idx >> 13, rem = idx & 8191;
    int co = rem >> 5, w5 = rem & 31;
    int k = ks >> 3;                          // CSTEPS = 8
    int ci = ((ks & 7) << 5) + w5;
    wct[idx] = (f16)W[((size_t)co * NCH + ci) * 3 + k];
}

__global__ __launch_bounds__(256) void prep_wf1p(const float* __restrict__ Wf1,
                                                 f16* __restrict__ dst) {
    __shared__ f16 t[NCH * 122];
    const int f = blockIdx.x, tid = threadIdx.x;
    const float* src = Wf1 + (size_t)f * FCK;
    for (int idx = tid; idx < FCK; idx += 256) {
        int co = idx / 121, l = idx - co * 121;
        t[co * 122 + l] = (f16)src[idx];
    }
    __syncthreads();
    for (int idx = tid; idx < FCK; idx += 256) {   // idx = kt
        int l = idx >> 8, co = idx & 255;
        int ck = idx >> 5, w5 = idx & 31;
        dst[(size_t)ck * 16384 + f * 32 + w5] = t[co * 122 + l];
    }
}

__global__ __launch_bounds__(256) void prep_xh(const float* __restrict__ x,
                                               f16* __restrict__ xh) {
    size_t g = (size_t)blockIdx.x * 256 + threadIdx.x;
    size_t N = (size_t)B_SZ * 8192;
    if (g * 4 >= N + 64) return;
    if (g * 4 < N) {
        float4 v = *(const float4*)(x + g * 4);
        f16x4 h = { (f16)v.x, (f16)v.y, (f16)v.z, (f16)v.w };
        *(f16x4*)(xh + g * 4) = h;
    } else {
        f16x4 z = { (f16)0.f, (f16)0.f, (f16)0.f, (f16)0.f };
        *(f16x4*)(xh + g * 4) = z;
    }
}

// ---------------------------------------------------------------------------
// Conv / pointwise: wave tile 128l x 128co, 1 wave/SIMD (the R11 change).
// Block = one b, 128 thr = 2 waves (co halves). A: [SROWS][CIN] LDS,
// XOR-swizzled, staged once. B: chunk-major global->regs, depth-2 prefetch
// (2 buffers, post-cluster issue), waits pinned by sched_barrier.
// acc[8][8] = 256 VGPR; total ~380 (no spill, 1 wave/SIMD by design).
// ---------------------------------------------------------------------------
#define CSTEP(BC, KS)                                                         \
  {                                                                           \
    const int k_ = (KS) / CSTEPS, cb_ = ((KS) % CSTEPS) * 4;                  \
    f16x8 a_[8];                                                              \
    _Pragma("unroll")                                                         \
    for (int m = 0; m < 8; ++m) {                                             \
      const int r_ = 16 * m + lr + k_;                                        \
      a_[m] = *(const f16x8*)(ins + r_ * CIN + (((cb_ + lh) ^ (r_ & 7)) << 3)); \
    }                                                                         \
    __builtin_amdgcn_sched_barrier(0);                                        \
    asm volatile("s_waitcnt vmcnt(8) lgkmcnt(0)" ::: "memory");               \
    __builtin_amdgcn_sched_barrier(0);                                        \
    __builtin_amdgcn_s_setprio(1);                                            \
    _Pragma("unroll")                                                         \
    for (int n = 0; n < 8; ++n)                                               \
      _Pragma("unroll")                                                       \
      for (int m = 0; m < 8; ++m)                                             \
        acc[m][n] = __builtin_amdgcn_mfma_f32_16x16x32_f16(a_[m], BC[n],      \
                                                           acc[m][n], 0, 0, 0); \
    __builtin_amdgcn_s_setprio(0);                                            \
    __builtin_amdgcn_sched_barrier(0);                                        \
    if ((KS) + 2 < KSTEPS) {                                                  \
      const f16* wp_ = wbase + (size_t)((KS) + 2) * 8192;                     \
      _Pragma("unroll")                                                       \
      for (int n = 0; n < 8; ++n) BC[n] = *(const f16x8*)(wp_ + n * 512);     \
    }                                                                         \
    __builtin_amdgcn_sched_barrier(0);                                        \
  }

template <int KSTEPS, int CSTEPS, int UPR, int CIN, int SROWS, int LIN,
          int LOUT, bool ISPW>
__global__ __launch_bounds__(128, 1) void convk(const f16* __restrict__ in,
                                                long in_bstride,
                                                const f16* __restrict__ wt,
                                                const float* __restrict__ bias,
                                                f16* __restrict__ out) {
    __shared__ f16 ins[SROWS * CIN];
    const int b    = blockIdx.x;
    const int tid  = threadIdx.x;
    const int lane = tid & 63, w = tid >> 6;     // 2 waves
    const int wc0  = w * 128;                    // wave's 128-co slice
    const int lr   = lane & 15, lh = lane >> 4;
    const f16* inb = in + (size_t)b * in_bstride;

    // B(0), B(1) prefetch (global->regs) — drained at the barrier (prologue)
    const f16* wbase = wt + (size_t)(wc0 + lr) * 32 + lh * 8;
    f16x8 bbA[8], bbB[8];
#pragma unroll
    for (int n = 0; n < 8; ++n) bbA[n] = *(const f16x8*)(wbase + n * 512);
#pragma unroll
    for (int n = 0; n < 8; ++n) bbB[n] = *(const f16x8*)(wbase + 8192 + n * 512);

    // stage full A tile, XOR-swizzled (16B units, unit ^= row&7)
    for (int u = tid; u < SROWS * UPR; u += 128) {
        int r = u / UPR, sl = u % UPR;
        const f16* src;
        if (ISPW) {
            src = (sl < 8) ? inb + (size_t)r * 64 + sl * 8
                           : inb - 64 + (sl - 8) * 8;   // x0 block
        } else {
            int sr = (r < LIN) ? r : (LIN - 1);          // clamp pad rows
            src = inb + (size_t)sr * CIN + sl * 8;
        }
        *(f16x8*)(ins + r * CIN + ((sl ^ (r & 7)) << 3)) = *(const f16x8*)src;
    }
    __syncthreads();                             // A visible

    f32x4 acc[8][8];
#pragma unroll
    for (int m = 0; m < 8; ++m)
#pragma unroll
        for (int n = 0; n < 8; ++n) acc[m][n] = (f32x4){0.f, 0.f, 0.f, 0.f};

#pragma unroll 1
    for (int ks = 0; ks < KSTEPS; ks += 2) {
        CSTEP(bbA, ks)
        CSTEP(bbB, ks + 1)
    }

    // epilogue: +bias, relu, fp16 store to [b][l][256]
    f16* ob = out + (size_t)b * LOUT * NCH;
#pragma unroll
    for (int n = 0; n < 8; ++n) {
        const int co = wc0 + 16 * n + lr;
        const float e = bias[co];
#pragma unroll
        for (int m = 0; m < 8; ++m)
#pragma unroll
            for (int r = 0; r < 4; ++r) {
                const int l = 16 * m + lh * 4 + r;
                if (l < LOUT) {
                    float v = fmaxf(acc[m][n][r] + e, 0.f);
                    ob[(size_t)l * NCH + co] = (f16)v;
                }
            }
    }
}

// ---------------------------------------------------------------------------
// FC1 (unchanged): tile 128b x 512f, 512 thr = 8 waves,
// A via gl16 dbuf, B chunk-major global->regs, counted vmcnt.
// ---------------------------------------------------------------------------
#define FSTEP(BC, BN, IT)                                                     \
  {                                                                           \
    const int itn_  = ((IT) + 1 < kc) ? (IT) + 1 : 0;                         \
    const int ckn_  = ck0 + itn_;                                             \
    const int bufn_ = ((IT) + 1) & 1;                                         \
    {                                                                         \
      int row_ = tid >> 2, cu_ = tid & 3;                                     \
      gl16(A + (size_t)(m0 + row_) * FCK + (size_t)ckn_ * 32                  \
               + ((cu_ ^ (row_ & 3)) << 3),                                   \
           Asl + bufn_ * 4096 + (w << 9));                                    \
    }                                                                         \
    const f16* wp_ = wfb + (size_t)ckn_ * 16384;                              \
    _Pragma("unroll")                                                         \
    for (int n = 0; n < 8; ++n) BN[n] = *(const f16x8*)(wp_ + n * 512);       \
    __builtin_amdgcn_sched_barrier(0);                                        \
    asm volatile("s_waitcnt vmcnt(9)" ::: "memory");                          \
    __builtin_amdgcn_sched_barrier(0);                                        \
    __builtin_amdgcn_s_barrier();                                             \
    const f16* ab_ = Asl + ((IT) & 1) * 4096;                                 \
    f16x8 a_[4];                                                              \
    _Pragma("unroll")                                                         \
    for (int m = 0; m < 4; ++m) {                                             \
      const int row_ = wb0 + 16 * m + lr;                                     \
      a_[m] = *(const f16x8*)(ab_ + row_ * 32 + ((lh ^ (row_ & 3)) << 3));    \
    }                                                                         \
    __builtin_amdgcn_s_setprio(1);                                            \
    _Pragma("unroll")                                                         \
    for (int n = 0; n < 8; ++n)                                               \
      _Pragma("unroll")                                                       \
      for (int m = 0; m < 4; ++m)                                             \
        acc[m][n] = __builtin_amdgcn_mfma_f32_16x16x32_f16(a_[m], BC[n],      \
                                                           acc[m][n], 0, 0, 0); \
    __builtin_amdgcn_s_setprio(0);                                            \
    __builtin_amdgcn_sched_barrier(0);                                        \
    __builtin_amdgcn_s_barrier();                                             \
  }

__global__ __launch_bounds__(512, 2) void fc1k(const f16* __restrict__ A,
                                               const f16* __restrict__ wf1p,
                                               float* __restrict__ part,
                                               int CB) {
    __shared__ f16 Asl[2 * 4096];                // 2 x 8KB (128b x 32k)
    const int m0  = blockIdx.x * 128;
    const int sp  = blockIdx.y;
    const int tid = threadIdx.x;
    const int lane = tid & 63, w = tid >> 6;
    const int wb0  = (w >> 2) * 64;              // b-half
    const int wf0  = (w & 3) * 128;              // f-quarter
    const int lr   = lane & 15, lh = lane >> 4;
    const int ck0  = sp * KPS;
    const int kc   = min(KPS, KCH - ck0);

    const f16* wfb = wf1p + (size_t)(wf0 + lr) * 32 + lh * 8;

    f32x4 acc[4][8];
#pragma unroll
    for (int m = 0; m < 4; ++m)
#pragma unroll
        for (int n = 0; n < 8; ++n) acc[m][n] = (f32x4){0.f, 0.f, 0.f, 0.f};

    {
        int row_ = tid >> 2, cu_ = tid & 3;
        gl16(A + (size_t)(m0 + row_) * FCK + (size_t)ck0 * 32
                 + ((cu_ ^ (row_ & 3)) << 3),
             Asl + (w << 9));
    }
    f16x8 b0[8], b1[8];
    const f16* wp0 = wfb + (size_t)ck0 * 16384;
#pragma unroll
    for (int n = 0; n < 8; ++n) b0[n] = *(const f16x8*)(wp0 + n * 512);
    __syncthreads();                             // drains prologue vmem

    int it = 0;
#pragma unroll 1
    for (; it + 2 <= kc; it += 2) {
        FSTEP(b0, b1, it)
        FSTEP(b1, b0, it + 1)
    }
    if (it < kc) FSTEP(b0, b1, it)

#pragma unroll
    for (int m = 0; m < 4; ++m)
#pragma unroll
        for (int n = 0; n < 8; ++n)
#pragma unroll
            for (int r = 0; r < 4; ++r) {
                const int bl = m0 + wb0 + 16 * m + lh * 4 + r;
                const int f  = wf0 + 16 * n + lr;
                part[((size_t)sp * CB + bl) * F1_ + f] = acc[m][n][r];
            }
}

// h4[m,f] = relu(bf1[f] + sum_sp part[sp][m][f])
__global__ __launch_bounds__(256) void fc1_reduce_kernel(const float* __restrict__ part,
                                                         const float* __restrict__ bf1,
                                                         float* __restrict__ h4,
                                                         int CB) {
    int idx = blockIdx.x * 256 + threadIdx.x;
    int f = idx & (F1_ - 1);
    float s = bf1[f];
#pragma unroll
    for (int sp = 0; sp < SPLIT; ++sp)
        s += part[(size_t)sp * CB * F1_ + idx];
    h4[idx] = fmaxf(s, 0.f);
}

// out[b] = bf2 + h4[b,:] . Wf2
__global__ __launch_bounds__(256) void fc2_kernel(const float* __restrict__ h4,
                                                  const float* __restrict__ Wf2,
                                                  const float* __restrict__ bf2,
                                                  float* __restrict__ out) {
    const int b    = blockIdx.x * 4 + (threadIdx.x >> 6);
    const int lane = threadIdx.x & 63;
    float s = 0.f;
#pragma unroll
    for (int i = 0; i < 8; ++i) s = fmaf(h4[(size_t)b * F1_ + lane + 64 * i],
                                         Wf2[lane + 64 * i], s);
#pragma unroll
    for (int o = 32; o > 0; o >>= 1) s += __shfl_xor(s, o);
    if (lane == 0) out[b] = s + bf2[0];
}

// ---------------------------------------------------------------------------
extern "C" void kernel_launch(void* const* d_in, const int* in_sizes, int n_in,
                              void* d_out, int out_size, void* d_ws, size_t ws_size,
                              hipStream_t stream) {
    const float* x   = (const float*)d_in[0];
    const float* Wp  = (const float*)d_in[1];
    const float* bp  = (const float*)d_in[2];
    const float* W1  = (const float*)d_in[3];
    const float* b1  = (const float*)d_in[4];
    const float* W2  = (const float*)d_in[5];
    const float* b2  = (const float*)d_in[6];
    const float* W3  = (const float*)d_in[7];
    const float* b3  = (const float*)d_in[8];
    const float* Wf1 = (const float*)d_in[9];
    const float* bf1 = (const float*)d_in[10];
    const float* Wf2 = (const float*)d_in[11];
    const float* bf2 = (const float*)d_in[12];
    float* out = (float*)d_out;

    // ---- workspace layout ----------------------------------------------
    char* base = (char*)d_ws;
    size_t off = 0;
    auto alloc = [&](size_t bytes) {
        size_t o = off; off = (off + bytes + 255) & ~(size_t)255; return o;
    };
    const size_t o_wpw  = alloc((size_t)NCH * 128 * 2);
    const size_t o_wct1 = alloc((size_t)NCH * 768 * 2);
    const size_t o_wct2 = alloc((size_t)NCH * 768 * 2);
    const size_t o_wct3 = alloc((size_t)NCH * 768 * 2);
    const size_t o_wf1p = alloc((size_t)F1_ * FCK * 2);
    const size_t o_xh   = alloc(((size_t)B_SZ * 8192 + 64) * 2);
    const size_t o_h4   = alloc((size_t)B_SZ * F1_ * 4);
    const size_t fixed  = off;

    // part (SPLIT x CB x 512 f32) overlays buf0 (dead during FC1)
    int CB = 0;
    const int cand[5] = {2048, 1024, 512, 256, 128};
    for (int i = 0; i < 5; ++i) {
        size_t c = (size_t)cand[i];
        size_t need = fixed
            + ((c * (size_t)L0_ * NCH * 2 + 255) & ~(size_t)255)     // buf0
            + ((c * (size_t)L1_ * NCH * 2 + 255) & ~(size_t)255);    // buf1
        if (need <= ws_size) { CB = cand[i]; break; }
    }
    if (CB == 0) return;
    const int nchunk = B_SZ / CB;

    const size_t o_buf0 = alloc((size_t)CB * L0_ * NCH * 2);
    const size_t o_buf1 = alloc((size_t)CB * L1_ * NCH * 2);

    f16*   wpw  = (f16*)(base + o_wpw);
    f16*   wct1 = (f16*)(base + o_wct1);
    f16*   wct2 = (f16*)(base + o_wct2);
    f16*   wct3 = (f16*)(base + o_wct3);
    f16*   wf1p = (f16*)(base + o_wf1p);
    f16*   xh   = (f16*)(base + o_xh);
    float* h4   = (float*)(base + o_h4);
    f16*   buf0 = (f16*)(base + o_buf0);
    f16*   buf1 = (f16*)(base + o_buf1);
    float* part = (float*)(base + o_buf0);       // overlay (buf0 dead in FC1)

    // ---- preps ---------------------------------------------------------
    prep_wpw<<<128, 256, 0, stream>>>(Wp, wpw);
    prep_wct<<<768, 256, 0, stream>>>(W1, wct1);
    prep_wct<<<768, 256, 0, stream>>>(W2, wct2);
    prep_wct<<<768, 256, 0, stream>>>(W3, wct3);
    prep_wf1p<<<F1_, 256, 0, stream>>>(Wf1, wf1p);
    prep_xh<<<(int)((((size_t)B_SZ * 8192 + 64) / 4 + 255) / 256), 256, 0, stream>>>(x, xh);

    // ---- chunked pipeline ----------------------------------------------
    for (int c = 0; c < nchunk; ++c) {
        const size_t b0 = (size_t)c * CB;
        // pointwise as K=128 GEMM: in = xh[b][(l+1)*64..]; x0 at in-64
        convk<4, 4, 16, 128, 128, 128, L0_, true><<<CB, 128, 0, stream>>>(
            xh + b0 * 8192 + 64, 8192, wpw, bp, buf0);
        convk<24, 8, 32, 256, 130, L0_, L1_, false><<<CB, 128, 0, stream>>>(
            buf0, (long)L0_ * NCH, wct1, b1, buf1);
        convk<24, 8, 32, 256, 130, L1_, L2_, false><<<CB, 128, 0, stream>>>(
            buf1, (long)L1_ * NCH, wct2, b2, buf0);
        convk<24, 8, 32, 256, 130, L2_, L3_, false><<<CB, 128, 0, stream>>>(
            buf0, (long)L2_ * NCH, wct3, b3, buf1);
        // conv3 output [l][co] IS the FC1 A layout (wf1p kt-order matches)
        fc1k<<<dim3(CB / 128, SPLIT), 512, 0, stream>>>(buf1, wf1p, part, CB);
        fc1_reduce_kernel<<<CB * 2, 256, 0, stream>>>(part, bf1, h4 + b0 * F1_, CB);
    }

    fc2_kernel<<<B_SZ / 4, 256, 0, stream>>>(h4, Wf2, bf2, out);
}

// Round 12
// 941.406 us; speedup vs baseline: 1.9960x; 1.9960x over previous
//
#include <hip/hip_runtime.h>

typedef _Float16 f16;
typedef _Float16 f16x8 __attribute__((ext_vector_type(8)));
typedef _Float16 f16x4 __attribute__((ext_vector_type(4)));
typedef float    f32x4 __attribute__((ext_vector_type(4)));

#define B_SZ   2048
#define NCH    256
#define L0_    127
#define L1_    125
#define L2_    123
#define L3_    121
#define F1_    512
#define FCK    30976
#define KCH    968         // 30976 / 32 k-chunks
#define SPLIT  16          // split-K for FC1
#define KPS    61          // ceil(968/16); last split has 53

// async global->LDS, 16B per lane; dest = wave-uniform base + lane*16
__device__ __forceinline__ void gl16(const f16* g, f16* l) {
    __builtin_amdgcn_global_load_lds(
        (const __attribute__((address_space(1))) void*)g,
        (__attribute__((address_space(3))) void*)l, 16, 0, 0);
}

// ---------------------------------------------------------------------------
// preps
// ---------------------------------------------------------------------------
__global__ __launch_bounds__(256) void prep_wpw(const float* __restrict__ Wp,
                                                f16* __restrict__ wpw) {
    int idx = blockIdx.x * 256 + threadIdx.x;
    if (idx >= NCH * 128) return;
    int c = idx >> 7, j = idx & 127;
    float v = (j < 64) ? Wp[c * 128 + j * 2 + 1] : Wp[c * 128 + (j - 64) * 2];
    wpw[idx] = (f16)v;
}

// merged: all three conv-weight transposes in one launch
__global__ __launch_bounds__(256) void prep_wct3(const float* __restrict__ W1,
                                                 const float* __restrict__ W2,
                                                 const float* __restrict__ W3,
                                                 f16* __restrict__ wct1,
                                                 f16* __restrict__ wct2,
                                                 f16* __restrict__ wct3) {
    int g = blockIdx.x;
    const float* W = (g < 768) ? W1 : (g < 1536) ? W2 : W3;
    f16* dst = (g < 768) ? wct1 : (g < 1536) ? wct2 : wct3;
    int idx = (g % 768) * 256 + threadIdx.x;
    if (idx >= NCH * 768) return;
    int co = idx / 768, rem = idx - co * 768;
    int k = rem >> 8, ci = rem & 255;
    dst[idx] = (f16)W[((size_t)co * NCH + ci) * 3 + k];
}

__global__ __launch_bounds__(256) void prep_wf1k(const float* __restrict__ Wf1,
                                                 f16* __restrict__ wf1h) {
    __shared__ f16 t[NCH * 122];
    const int f = blockIdx.x, tid = threadIdx.x;
    const float* src = Wf1 + (size_t)f * FCK;
    for (int idx = tid; idx < FCK; idx += 256) {
        int co = idx / 121, l = idx - co * 121;
        t[co * 122 + l] = (f16)src[idx];
    }
    __syncthreads();
    f16* dst = wf1h + (size_t)f * FCK;
    for (int idx = tid; idx < FCK; idx += 256) {
        int l = idx >> 8, co = idx & 255;
        dst[idx] = t[co * 122 + l];
    }
}

__global__ __launch_bounds__(256) void prep_xh(const float* __restrict__ x,
                                               f16* __restrict__ xh) {
    size_t g = (size_t)blockIdx.x * 256 + threadIdx.x;
    size_t N = (size_t)B_SZ * 8192;
    if (g * 4 >= N + 64) return;
    if (g * 4 < N) {
        float4 v = *(const float4*)(x + g * 4);
        f16x4 h = { (f16)v.x, (f16)v.y, (f16)v.z, (f16)v.w };
        *(f16x4*)(xh + g * 4) = h;
    } else {
        f16x4 z = { (f16)0.f, (f16)0.f, (f16)0.f, (f16)0.f };
        *(f16x4*)(xh + g * 4) = z;
    }
}

// ---------------------------------------------------------------------------
// Conv / pointwise (R7 verbatim — best measured: 131 µs/layer).
// Block = (b, 64-l half), 256 thr = 4 waves; wave tile 64l x 64co.
// A half-tile LDS-resident; B double-buffered via global_load_lds.
// Loop: stage(ks+1); vmcnt(4); barrier; ds_read+MFMA; barrier.
// ---------------------------------------------------------------------------
template <int KSTEPS, int CSTEPS, int UPR, int PADC, int SROWS, int LIN,
          int LOUT, bool ISPW>
__global__ __launch_bounds__(256) void convk(const f16* __restrict__ in,
                                             long in_bstride,
                                             const f16* __restrict__ wt,
                                             const float* __restrict__ bias,
                                             f16* __restrict__ out) {
    constexpr int KT = KSTEPS * 32;
    __shared__ f16 ins[SROWS * PADC];
    __shared__ f16 wlds[2 * 8192];          // 2 x (256co x 32k)

    const int b    = blockIdx.x;
    const int lh0  = blockIdx.y * 64;       // which 64-l half
    const int tid  = threadIdx.x;
    const int lane = tid & 63, w = tid >> 6;
    const int wc0  = w * 64;                // wave's 64-co slice
    const int lr   = lane & 15, lh = lane >> 4;
    const f16* inb = in + (size_t)b * in_bstride;

    auto stageB = [&](int ks, int buf) {
        f16* dst0 = wlds + buf * 8192 + (w << 6) * 8;
#pragma unroll
        for (int j = 0; j < 4; ++j) {
            int u = j * 256 + w * 64 + lane;
            int row = u >> 2, cu = u & 3;
            int cs = cu ^ ((row >> 2) & 3);
            gl16(wt + (size_t)row * KT + ks * 32 + cs * 8, dst0 + j * 2048);
        }
    };

    stageB(0, 0);
    for (int u = tid; u < SROWS * UPR; u += 256) {
        int r = u / UPR, sl = u % UPR;
        const f16* src;
        if (ISPW) {
            int sr = lh0 + r;               // row 127 reads the zero pad: ok
            src = (sl < 8) ? inb + (size_t)sr * 64 + sl * 8
                           : inb - 64 + (sl - 8) * 8;        // x0 block
        } else {
            int sr = lh0 + r; if (sr > LIN - 1) sr = LIN - 1;
            src = inb + (size_t)sr * NCH + sl * 8;
        }
        *(f16x8*)(ins + r * PADC + sl * 8) = *(const f16x8*)src;
    }
    __syncthreads();                        // drains everything incl. stageB(0)

    f32x4 acc[4][4];
#pragma unroll
    for (int m = 0; m < 4; ++m)
#pragma unroll
        for (int n = 0; n < 4; ++n) acc[m][n] = (f32x4){0.f, 0.f, 0.f, 0.f};

#pragma unroll 1
    for (int ks = 0; ks < KSTEPS; ++ks) {
        const int buf = ks & 1;
        if (ks + 1 < KSTEPS) {
            stageB(ks + 1, buf ^ 1);
            asm volatile("s_waitcnt vmcnt(4)" ::: "memory");
        } else {
            asm volatile("s_waitcnt vmcnt(0)" ::: "memory");
        }
        __builtin_amdgcn_sched_barrier(0);
        __builtin_amdgcn_s_barrier();
        __builtin_amdgcn_sched_barrier(0);

        const int k = ks / CSTEPS, ci0 = (ks % CSTEPS) * 32;
        f16x8 a[4], bf[4];
#pragma unroll
        for (int m = 0; m < 4; ++m)
            a[m] = *(const f16x8*)(ins + (16 * m + lr + k) * PADC
                                   + ci0 + lh * 8);
#pragma unroll
        for (int n = 0; n < 4; ++n) {
            const int co = wc0 + 16 * n + lr;
            bf[n] = *(const f16x8*)(wlds + buf * 8192
                                    + (co * 4 + (lh ^ ((co >> 2) & 3))) * 8);
        }
        __builtin_amdgcn_s_setprio(1);
#pragma unroll
        for (int n = 0; n < 4; ++n)
#pragma unroll
            for (int m = 0; m < 4; ++m)
                acc[m][n] = __builtin_amdgcn_mfma_f32_16x16x32_f16(
                    a[m], bf[n], acc[m][n], 0, 0, 0);
        __builtin_amdgcn_s_setprio(0);
        __builtin_amdgcn_sched_barrier(0);
        __builtin_amdgcn_s_barrier();
    }

    f16* ob = out + (size_t)b * LOUT * NCH;
#pragma unroll
    for (int n = 0; n < 4; ++n) {
        const int co = wc0 + 16 * n + lr;
        const float e = bias[co];
#pragma unroll
        for (int m = 0; m < 4; ++m)
#pragma unroll
            for (int r = 0; r < 4; ++r) {
                const int l = lh0 + 16 * m + lh * 4 + r;
                if (l < LOUT) {
                    float v = fmaxf(acc[m][n][r] + e, 0.f);
                    ob[(size_t)l * NCH + co] = (f16)v;
                }
            }
    }
}

// ---------------------------------------------------------------------------
// FC1 (R7 structure, SPLIT=16 with uneven tail). Block tile 128b x 256f,
// 512 thr = 8 waves (2x4 of 64x64). A(8KB)+B(16KB) dbuf via gl16.
// ---------------------------------------------------------------------------
__global__ __launch_bounds__(512) void fc1k(const f16* __restrict__ A,
                                            const f16* __restrict__ Bw,
                                            float* __restrict__ part,
                                            int CB) {
    __shared__ f16 Asl[2 * 4096];
    __shared__ f16 Bsl[2 * 8192];
    const int m0 = blockIdx.x * 128, n0 = blockIdx.y * 256, sp = blockIdx.z;
    const int tid  = threadIdx.x;
    const int lane = tid & 63, w = tid >> 6;
    const int wb0  = (w >> 2) * 64, wf0 = (w & 3) * 64;
    const int lr   = lane & 15, lh = lane >> 4;
    const int ck0  = sp * KPS;
    const int kc   = min(KPS, KCH - ck0);

    auto stage = [&](int it, int buf) {
        const int k0 = (ck0 + it) * 32;
        {   // A: 512 units, one round
            int u = tid;
            int row = u >> 2, cu = u & 3;
            int cs = cu ^ ((row >> 2) & 3);
            gl16(A + (size_t)(m0 + row) * FCK + k0 + cs * 8,
                 Asl + buf * 4096 + (w << 6) * 8);
        }
#pragma unroll
        for (int j = 0; j < 2; ++j) {       // B: 1024 units, two rounds
            int u = j * 512 + tid;
            int row = u >> 2, cu = u & 3;
            int cs = cu ^ ((row >> 2) & 3);
            gl16(Bw + (size_t)(n0 + row) * FCK + k0 + cs * 8,
                 Bsl + buf * 8192 + (j * 512 + (w << 6)) * 8);
        }
    };

    f32x4 acc[4][4];
#pragma unroll
    for (int m = 0; m < 4; ++m)
#pragma unroll
        for (int n = 0; n < 4; ++n) acc[m][n] = (f32x4){0.f, 0.f, 0.f, 0.f};

    stage(0, 0);
    __syncthreads();                        // drains stage(0)

#pragma unroll 1
    for (int it = 0; it < kc; ++it) {
        const int buf = it & 1;
        if (it + 1 < kc) {
            stage(it + 1, buf ^ 1);
            asm volatile("s_waitcnt vmcnt(3)" ::: "memory");
        } else {
            asm volatile("s_waitcnt vmcnt(0)" ::: "memory");
        }
        __builtin_amdgcn_sched_barrier(0);
        __builtin_amdgcn_s_barrier();
        __builtin_amdgcn_sched_barrier(0);

        f16x8 a[4], bf[4];
#pragma unroll
        for (int m = 0; m < 4; ++m) {
            const int row = wb0 + 16 * m + lr;
            a[m] = *(const f16x8*)(Asl + buf * 4096
                                   + (row * 4 + (lh ^ ((row >> 2) & 3))) * 8);
        }
#pragma unroll
        for (int n = 0; n < 4; ++n) {
            const int row = wf0 + 16 * n + lr;
            bf[n] = *(const f16x8*)(Bsl + buf * 8192
                                    + (row * 4 + (lh ^ ((row >> 2) & 3))) * 8);
        }
        __builtin_amdgcn_s_setprio(1);
#pragma unroll
        for (int m = 0; m < 4; ++m)
#pragma unroll
            for (int n = 0; n < 4; ++n)
                acc[m][n] = __builtin_amdgcn_mfma_f32_16x16x32_f16(
                    a[m], bf[n], acc[m][n], 0, 0, 0);
        __builtin_amdgcn_s_setprio(0);
        __builtin_amdgcn_sched_barrier(0);
        __builtin_amdgcn_s_barrier();
    }

#pragma unroll
    for (int m = 0; m < 4; ++m)
#pragma unroll
        for (int n = 0; n < 4; ++n)
#pragma unroll
            for (int r = 0; r < 4; ++r) {
                const int bl = m0 + wb0 + 16 * m + lh * 4 + r;
                const int f  = n0 + wf0 + 16 * n + lr;
                part[((size_t)sp * CB + bl) * F1_ + f] = acc[m][n][r];
            }
}

// h4[m,f] = relu(bf1[f] + sum_sp part[sp][m][f])  — float4-vectorized
__global__ __launch_bounds__(256) void fc1_reduce_kernel(const float* __restrict__ part,
                                                         const float* __restrict__ bf1,
                                                         float* __restrict__ h4,
                                                         int CB) {
    int idx4 = blockIdx.x * 256 + threadIdx.x;   // < CB*512/4
    int f4 = (idx4 * 4) & (F1_ - 1);
    float4 s = *(const float4*)(bf1 + f4);
#pragma unroll
    for (int sp = 0; sp < SPLIT; ++sp) {
        float4 p = *(const float4*)(part + (size_t)sp * CB * F1_ + (size_t)idx4 * 4);
        s.x += p.x; s.y += p.y; s.z += p.z; s.w += p.w;
    }
    float4 o = { fmaxf(s.x, 0.f), fmaxf(s.y, 0.f), fmaxf(s.z, 0.f), fmaxf(s.w, 0.f) };
    *(float4*)(h4 + (size_t)idx4 * 4) = o;
}

// out[b] = bf2 + h4[b,:] . Wf2
__global__ __launch_bounds__(256) void fc2_kernel(const float* __restrict__ h4,
                                                  const float* __restrict__ Wf2,
                                                  const float* __restrict__ bf2,
                                                  float* __restrict__ out) {
    const int b    = blockIdx.x * 4 + (threadIdx.x >> 6);
    const int lane = threadIdx.x & 63;
    float s = 0.f;
#pragma unroll
    for (int i = 0; i < 8; ++i) s = fmaf(h4[(size_t)b * F1_ + lane + 64 * i],
                                         Wf2[lane + 64 * i], s);
#pragma unroll
    for (int o = 32; o > 0; o >>= 1) s += __shfl_xor(s, o);
    if (lane == 0) out[b] = s + bf2[0];
}

// ---------------------------------------------------------------------------
extern "C" void kernel_launch(void* const* d_in, const int* in_sizes, int n_in,
                              void* d_out, int out_size, void* d_ws, size_t ws_size,
                              hipStream_t stream) {
    const float* x   = (const float*)d_in[0];
    const float* Wp  = (const float*)d_in[1];
    const float* bp  = (const float*)d_in[2];
    const float* W1  = (const float*)d_in[3];
    const float* b1  = (const float*)d_in[4];
    const float* W2  = (const float*)d_in[5];
    const float* b2  = (const float*)d_in[6];
    const float* W3  = (const float*)d_in[7];
    const float* b3  = (const float*)d_in[8];
    const float* Wf1 = (const float*)d_in[9];
    const float* bf1 = (const float*)d_in[10];
    const float* Wf2 = (const float*)d_in[11];
    const float* bf2 = (const float*)d_in[12];
    float* out = (float*)d_out;

    // ---- workspace layout ----------------------------------------------
    char* base = (char*)d_ws;
    size_t off = 0;
    auto alloc = [&](size_t bytes) {
        size_t o = off; off = (off + bytes + 255) & ~(size_t)255; return o;
    };
    const size_t o_wpw  = alloc((size_t)NCH * 128 * 2);
    const size_t o_wct1 = alloc((size_t)NCH * 768 * 2);
    const size_t o_wct2 = alloc((size_t)NCH * 768 * 2);
    const size_t o_wct3 = alloc((size_t)NCH * 768 * 2);
    const size_t o_wf1h = alloc((size_t)F1_ * FCK * 2);
    const size_t o_xh   = alloc(((size_t)B_SZ * 8192 + 64) * 2);
    const size_t o_h4   = alloc((size_t)B_SZ * F1_ * 4);
    const size_t fixed  = off;

    int CB = 0;
    const int cand[5] = {2048, 1024, 512, 256, 128};
    for (int i = 0; i < 5; ++i) {
        size_t c = (size_t)cand[i];
        size_t need = fixed
            + (((size_t)SPLIT * c * F1_ * 4 + 255) & ~(size_t)255)   // part
            + ((c * (size_t)L0_ * NCH * 2 + 255) & ~(size_t)255)     // buf0
            + ((c * (size_t)L1_ * NCH * 2 + 255) & ~(size_t)255);    // buf1
        if (need <= ws_size) { CB = cand[i]; break; }
    }
    if (CB == 0) return;
    const int nchunk = B_SZ / CB;

    const size_t o_part = alloc((size_t)SPLIT * CB * F1_ * 4);
    const size_t o_buf0 = alloc((size_t)CB * L0_ * NCH * 2);
    const size_t o_buf1 = alloc((size_t)CB * L1_ * NCH * 2);

    f16*   wpw  = (f16*)(base + o_wpw);
    f16*   wct1 = (f16*)(base + o_wct1);
    f16*   wct2 = (f16*)(base + o_wct2);
    f16*   wct3 = (f16*)(base + o_wct3);
    f16*   wf1h = (f16*)(base + o_wf1h);
    f16*   xh   = (f16*)(base + o_xh);
    float* h4   = (float*)(base + o_h4);
    float* part = (float*)(base + o_part);
    f16*   buf0 = (f16*)(base + o_buf0);
    f16*   buf1 = (f16*)(base + o_buf1);

    // ---- preps ---------------------------------------------------------
    prep_wpw<<<128, 256, 0, stream>>>(Wp, wpw);
    prep_wct3<<<2304, 256, 0, stream>>>(W1, W2, W3, wct1, wct2, wct3);
    prep_wf1k<<<F1_, 256, 0, stream>>>(Wf1, wf1h);
    prep_xh<<<(int)((((size_t)B_SZ * 8192 + 64) / 4 + 255) / 256), 256, 0, stream>>>(x, xh);

    // ---- chunked pipeline ----------------------------------------------
    for (int c = 0; c < nchunk; ++c) {
        const size_t b0 = (size_t)c * CB;
        // pointwise as K=128 GEMM: in = xh[b][(l+1)*64..]; x0 at in-64
        convk<4, 4, 16, 136, 64, 128, L0_, true><<<dim3(CB, 2), 256, 0, stream>>>(
            xh + b0 * 8192 + 64, 8192, wpw, bp, buf0);
        convk<24, 8, 32, 264, 66, L0_, L1_, false><<<dim3(CB, 2), 256, 0, stream>>>(
            buf0, (long)L0_ * NCH, wct1, b1, buf1);
        convk<24, 8, 32, 264, 66, L1_, L2_, false><<<dim3(CB, 2), 256, 0, stream>>>(
            buf1, (long)L1_ * NCH, wct2, b2, buf0);
        convk<24, 8, 32, 264, 66, L2_, L3_, false><<<dim3(CB, 2), 256, 0, stream>>>(
            buf0, (long)L2_ * NCH, wct3, b3, buf1);
        // conv3 output [l][co] IS the FC1 A layout (wf1h K-permuted at prep)
        fc1k<<<dim3(CB / 128, 2, SPLIT), 512, 0, stream>>>(buf1, wf1h, part, CB);
        fc1_reduce_kernel<<<CB * F1_ / 1024, 256, 0, stream>>>(part, bf1,
                                                               h4 + b0 * F1_, CB);
    }

    fc2_kernel<<<B_SZ / 4, 256, 0, stream>>>(h4, Wf2, bf2, out);
}

// Round 13
// 941.256 us; speedup vs baseline: 1.9963x; 1.0002x over previous
//
#include <hip/hip_runtime.h>

typedef _Float16 f16;
typedef _Float16 f16x8 __attribute__((ext_vector_type(8)));
typedef _Float16 f16x4 __attribute__((ext_vector_type(4)));
typedef float    f32x4 __attribute__((ext_vector_type(4)));

#define B_SZ   2048
#define NCH    256
#define L0_    127
#define L1_    125
#define L2_    123
#define L3_    121
#define F1_    512
#define FCK    30976
#define KCH    968         // 30976 / 32 k-chunks
#define SPLIT  16          // split-K for FC1
#define KPS    61          // ceil(968/16); last split has 53

// async global->LDS, 16B per lane; dest = wave-uniform base + lane*16
__device__ __forceinline__ void gl16(const f16* g, f16* l) {
    __builtin_amdgcn_global_load_lds(
        (const __attribute__((address_space(1))) void*)g,
        (__attribute__((address_space(3))) void*)l, 16, 0, 0);
}

// ---------------------------------------------------------------------------
// preps (R12 verbatim)
// ---------------------------------------------------------------------------
__global__ __launch_bounds__(256) void prep_wpw(const float* __restrict__ Wp,
                                                f16* __restrict__ wpw) {
    int idx = blockIdx.x * 256 + threadIdx.x;
    if (idx >= NCH * 128) return;
    int c = idx >> 7, j = idx & 127;
    float v = (j < 64) ? Wp[c * 128 + j * 2 + 1] : Wp[c * 128 + (j - 64) * 2];
    wpw[idx] = (f16)v;
}

__global__ __launch_bounds__(256) void prep_wct3(const float* __restrict__ W1,
                                                 const float* __restrict__ W2,
                                                 const float* __restrict__ W3,
                                                 f16* __restrict__ wct1,
                                                 f16* __restrict__ wct2,
                                                 f16* __restrict__ wct3) {
    int g = blockIdx.x;
    const float* W = (g < 768) ? W1 : (g < 1536) ? W2 : W3;
    f16* dst = (g < 768) ? wct1 : (g < 1536) ? wct2 : wct3;
    int idx = (g % 768) * 256 + threadIdx.x;
    if (idx >= NCH * 768) return;
    int co = idx / 768, rem = idx - co * 768;
    int k = rem >> 8, ci = rem & 255;
    dst[idx] = (f16)W[((size_t)co * NCH + ci) * 3 + k];
}

__global__ __launch_bounds__(256) void prep_wf1k(const float* __restrict__ Wf1,
                                                 f16* __restrict__ wf1h) {
    __shared__ f16 t[NCH * 122];
    const int f = blockIdx.x, tid = threadIdx.x;
    const float* src = Wf1 + (size_t)f * FCK;
    for (int idx = tid; idx < FCK; idx += 256) {
        int co = idx / 121, l = idx - co * 121;
        t[co * 122 + l] = (f16)src[idx];
    }
    __syncthreads();
    f16* dst = wf1h + (size_t)f * FCK;
    for (int idx = tid; idx < FCK; idx += 256) {
        int l = idx >> 8, co = idx & 255;
        dst[idx] = t[co * 122 + l];
    }
}

__global__ __launch_bounds__(256) void prep_xh(const float* __restrict__ x,
                                               f16* __restrict__ xh) {
    size_t g = (size_t)blockIdx.x * 256 + threadIdx.x;
    size_t N = (size_t)B_SZ * 8192;
    if (g * 4 >= N + 64) return;
    if (g * 4 < N) {
        float4 v = *(const float4*)(x + g * 4);
        f16x4 h = { (f16)v.x, (f16)v.y, (f16)v.z, (f16)v.w };
        *(f16x4*)(xh + g * 4) = h;
    } else {
        f16x4 z = { (f16)0.f, (f16)0.f, (f16)0.f, (f16)0.f };
        *(f16x4*)(xh + g * 4) = z;
    }
}

// ---------------------------------------------------------------------------
// Conv / pointwise: full-l block, 512 thr = 8 waves (2l x 4co of 64x64).
// A: [SROWS][CIN] LDS, XOR-swizzled (R8 scheme), staged once, resident.
// B: 3-buffer LDS rotation via gl16 (pre-swizzled source, linear dest,
//    swizzled read), DEPTH-2-in-flight counted vmcnt (m218 discipline):
//    issue stage(ks+2); vmcnt(4); barrier; ds_read+MFMA; barrier.
// ---------------------------------------------------------------------------
template <int KSTEPS, int CSTEPS, int UPR, int CIN, int SROWS, int LIN,
          int LOUT, bool ISPW>
__global__ __launch_bounds__(512) void convk(const f16* __restrict__ in,
                                             long in_bstride,
                                             const f16* __restrict__ wt,
                                             const float* __restrict__ bias,
                                             f16* __restrict__ out) {
    constexpr int KT = KSTEPS * 32;
    __shared__ f16 ins[SROWS * CIN];
    __shared__ f16 wlds[3 * 8192];          // 3 x (256co x 32k)

    const int b    = blockIdx.x;
    const int tid  = threadIdx.x;
    const int lane = tid & 63, w = tid >> 6;     // 8 waves
    const int wl0  = (w >> 2) * 64;              // 2 l-halves
    const int wc0  = (w & 3) * 64;               // 4 co-quarters
    const int lr   = lane & 15, lh = lane >> 4;
    const f16* inb = in + (size_t)b * in_bstride;

    // stage B chunk `ks` into rotating buffer (2 gl16/thread)
    auto stageB = [&](int ks, int buf) {
#pragma unroll
        for (int j = 0; j < 2; ++j) {
            int u = j * 512 + tid;
            int row = u >> 2, cu = u & 3;
            int cs = cu ^ ((row >> 2) & 3);
            gl16(wt + (size_t)row * KT + ks * 32 + cs * 8,
                 wlds + buf * 8192 + (size_t)(j * 512 + (w << 6)) * 8);
        }
    };

    stageB(0, 0);
    stageB(1, 1);
    // stage A tile, XOR-swizzled (16B units, unit ^= row&7)
    for (int u = tid; u < SROWS * UPR; u += 512) {
        int r = u / UPR, sl = u % UPR;
        const f16* src;
        if (ISPW) {
            src = (sl < 8) ? inb + (size_t)r * 64 + sl * 8
                           : inb - 64 + (sl - 8) * 8;        // x0 block
        } else {
            int sr = (r < LIN) ? r : (LIN - 1);
            src = inb + (size_t)sr * NCH + sl * 8;
        }
        *(f16x8*)(ins + r * CIN + ((sl ^ (r & 7)) << 3)) = *(const f16x8*)src;
    }
    __syncthreads();                        // drains everything (once/block)

    f32x4 acc[4][4];
#pragma unroll
    for (int m = 0; m < 4; ++m)
#pragma unroll
        for (int n = 0; n < 4; ++n) acc[m][n] = (f32x4){0.f, 0.f, 0.f, 0.f};

#pragma unroll 1
    for (int ks = 0; ks < KSTEPS; ++ks) {
        const int rbuf = ks % 3;
        if (ks < KSTEPS - 2) {
            stageB(ks + 2, (ks + 2) % 3);
            asm volatile("s_waitcnt vmcnt(4)" ::: "memory");
        } else if (ks == KSTEPS - 2) {
            asm volatile("s_waitcnt vmcnt(2)" ::: "memory");
        } else {
            asm volatile("s_waitcnt vmcnt(0)" ::: "memory");
        }
        __builtin_amdgcn_sched_barrier(0);
        __builtin_amdgcn_s_barrier();
        __builtin_amdgcn_sched_barrier(0);

        const int k = ks / CSTEPS, cb = (ks % CSTEPS) * 4;
        f16x8 a[4], bf[4];
#pragma unroll
        for (int m = 0; m < 4; ++m) {
            const int r_ = wl0 + 16 * m + lr + k;
            a[m] = *(const f16x8*)(ins + r_ * CIN + (((cb + lh) ^ (r_ & 7)) << 3));
        }
#pragma unroll
        for (int n = 0; n < 4; ++n) {
            const int co = wc0 + 16 * n + lr;
            bf[n] = *(const f16x8*)(wlds + rbuf * 8192
                                    + (co * 4 + (lh ^ ((co >> 2) & 3))) * 8);
        }
        __builtin_amdgcn_s_setprio(1);
#pragma unroll
        for (int n = 0; n < 4; ++n)
#pragma unroll
            for (int m = 0; m < 4; ++m)
                acc[m][n] = __builtin_amdgcn_mfma_f32_16x16x32_f16(
                    a[m], bf[n], acc[m][n], 0, 0, 0);
        __builtin_amdgcn_s_setprio(0);
        __builtin_amdgcn_sched_barrier(0);
        __builtin_amdgcn_s_barrier();
    }

    // epilogue: +bias, relu, fp16 store to [b][l][256]
    f16* ob = out + (size_t)b * LOUT * NCH;
#pragma unroll
    for (int n = 0; n < 4; ++n) {
        const int co = wc0 + 16 * n + lr;
        const float e = bias[co];
#pragma unroll
        for (int m = 0; m < 4; ++m)
#pragma unroll
            for (int r = 0; r < 4; ++r) {
                const int l = wl0 + 16 * m + lh * 4 + r;
                if (l < LOUT) {
                    float v = fmaxf(acc[m][n][r] + e, 0.f);
                    ob[(size_t)l * NCH + co] = (f16)v;
                }
            }
    }
}

// ---------------------------------------------------------------------------
// FC1 (R12 verbatim). Block tile 128b x 256f, 512 thr = 8 waves.
// ---------------------------------------------------------------------------
__global__ __launch_bounds__(512) void fc1k(const f16* __restrict__ A,
                                            const f16* __restrict__ Bw,
                                            float* __restrict__ part,
                                            int CB) {
    __shared__ f16 Asl[2 * 4096];
    __shared__ f16 Bsl[2 * 8192];
    const int m0 = blockIdx.x * 128, n0 = blockIdx.y * 256, sp = blockIdx.z;
    const int tid  = threadIdx.x;
    const int lane = tid & 63, w = tid >> 6;
    const int wb0  = (w >> 2) * 64, wf0 = (w & 3) * 64;
    const int lr   = lane & 15, lh = lane >> 4;
    const int ck0  = sp * KPS;
    const int kc   = min(KPS, KCH - ck0);

    auto stage = [&](int it, int buf) {
        const int k0 = (ck0 + it) * 32;
        {
            int u = tid;
            int row = u >> 2, cu = u & 3;
            int cs = cu ^ ((row >> 2) & 3);
            gl16(A + (size_t)(m0 + row) * FCK + k0 + cs * 8,
                 Asl + buf * 4096 + (w << 6) * 8);
        }
#pragma unroll
        for (int j = 0; j < 2; ++j) {
            int u = j * 512 + tid;
            int row = u >> 2, cu = u & 3;
            int cs = cu ^ ((row >> 2) & 3);
            gl16(Bw + (size_t)(n0 + row) * FCK + k0 + cs * 8,
                 Bsl + buf * 8192 + (j * 512 + (w << 6)) * 8);
        }
    };

    f32x4 acc[4][4];
#pragma unroll
    for (int m = 0; m < 4; ++m)
#pragma unroll
        for (int n = 0; n < 4; ++n) acc[m][n] = (f32x4){0.f, 0.f, 0.f, 0.f};

    stage(0, 0);
    __syncthreads();

#pragma unroll 1
    for (int it = 0; it < kc; ++it) {
        const int buf = it & 1;
        if (it + 1 < kc) {
            stage(it + 1, buf ^ 1);
            asm volatile("s_waitcnt vmcnt(3)" ::: "memory");
        } else {
            asm volatile("s_waitcnt vmcnt(0)" ::: "memory");
        }
        __builtin_amdgcn_sched_barrier(0);
        __builtin_amdgcn_s_barrier();
        __builtin_amdgcn_sched_barrier(0);

        f16x8 a[4], bf[4];
#pragma unroll
        for (int m = 0; m < 4; ++m) {
            const int row = wb0 + 16 * m + lr;
            a[m] = *(const f16x8*)(Asl + buf * 4096
                                   + (row * 4 + (lh ^ ((row >> 2) & 3))) * 8);
        }
#pragma unroll
        for (int n = 0; n < 4; ++n) {
            const int row = wf0 + 16 * n + lr;
            bf[n] = *(const f16x8*)(Bsl + buf * 8192
                                    + (row * 4 + (lh ^ ((row >> 2) & 3))) * 8);
        }
        __builtin_amdgcn_s_setprio(1);
#pragma unroll
        for (int m = 0; m < 4; ++m)
#pragma unroll
            for (int n = 0; n < 4; ++n)
                acc[m][n] = __builtin_amdgcn_mfma_f32_16x16x32_f16(
                    a[m], bf[n], acc[m][n], 0, 0, 0);
        __builtin_amdgcn_s_setprio(0);
        __builtin_amdgcn_sched_barrier(0);
        __builtin_amdgcn_s_barrier();
    }

#pragma unroll
    for (int m = 0; m < 4; ++m)
#pragma unroll
        for (int n = 0; n < 4; ++n)
#pragma unroll
            for (int r = 0; r < 4; ++r) {
                const int bl = m0 + wb0 + 16 * m + lh * 4 + r;
                const int f  = n0 + wf0 + 16 * n + lr;
                part[((size_t)sp * CB + bl) * F1_ + f] = acc[m][n][r];
            }
}

// h4[m,f] = relu(bf1[f] + sum_sp part[sp][m][f])  — float4-vectorized
__global__ __launch_bounds__(256) void fc1_reduce_kernel(const float* __restrict__ part,
                                                         const float* __restrict__ bf1,
                                                         float* __restrict__ h4,
                                                         int CB) {
    int idx4 = blockIdx.x * 256 + threadIdx.x;
    int f4 = (idx4 * 4) & (F1_ - 1);
    float4 s = *(const float4*)(bf1 + f4);
#pragma unroll
    for (int sp = 0; sp < SPLIT; ++sp) {
        float4 p = *(const float4*)(part + (size_t)sp * CB * F1_ + (size_t)idx4 * 4);
        s.x += p.x; s.y += p.y; s.z += p.z; s.w += p.w;
    }
    float4 o = { fmaxf(s.x, 0.f), fmaxf(s.y, 0.f), fmaxf(s.z, 0.f), fmaxf(s.w, 0.f) };
    *(float4*)(h4 + (size_t)idx4 * 4) = o;
}

// out[b] = bf2 + h4[b,:] . Wf2
__global__ __launch_bounds__(256) void fc2_kernel(const float* __restrict__ h4,
                                                  const float* __restrict__ Wf2,
                                                  const float* __restrict__ bf2,
                                                  float* __restrict__ out) {
    const int b    = blockIdx.x * 4 + (threadIdx.x >> 6);
    const int lane = threadIdx.x & 63;
    float s = 0.f;
#pragma unroll
    for (int i = 0; i < 8; ++i) s = fmaf(h4[(size_t)b * F1_ + lane + 64 * i],
                                         Wf2[lane + 64 * i], s);
#pragma unroll
    for (int o = 32; o > 0; o >>= 1) s += __shfl_xor(s, o);
    if (lane == 0) out[b] = s + bf2[0];
}

// ---------------------------------------------------------------------------
extern "C" void kernel_launch(void* const* d_in, const int* in_sizes, int n_in,
                              void* d_out, int out_size, void* d_ws, size_t ws_size,
                              hipStream_t stream) {
    const float* x   = (const float*)d_in[0];
    const float* Wp  = (const float*)d_in[1];
    const float* bp  = (const float*)d_in[2];
    const float* W1  = (const float*)d_in[3];
    const float* b1  = (const float*)d_in[4];
    const float* W2  = (const float*)d_in[5];
    const float* b2  = (const float*)d_in[6];
    const float* W3  = (const float*)d_in[7];
    const float* b3  = (const float*)d_in[8];
    const float* Wf1 = (const float*)d_in[9];
    const float* bf1 = (const float*)d_in[10];
    const float* Wf2 = (const float*)d_in[11];
    const float* bf2 = (const float*)d_in[12];
    float* out = (float*)d_out;

    // ---- workspace layout ----------------------------------------------
    char* base = (char*)d_ws;
    size_t off = 0;
    auto alloc = [&](size_t bytes) {
        size_t o = off; off = (off + bytes + 255) & ~(size_t)255; return o;
    };
    const size_t o_wpw  = alloc((size_t)NCH * 128 * 2);
    const size_t o_wct1 = alloc((size_t)NCH * 768 * 2);
    const size_t o_wct2 = alloc((size_t)NCH * 768 * 2);
    const size_t o_wct3 = alloc((size_t)NCH * 768 * 2);
    const size_t o_wf1h = alloc((size_t)F1_ * FCK * 2);
    const size_t o_xh   = alloc(((size_t)B_SZ * 8192 + 64) * 2);
    const size_t o_h4   = alloc((size_t)B_SZ * F1_ * 4);
    const size_t fixed  = off;

    int CB = 0;
    const int cand[5] = {2048, 1024, 512, 256, 128};
    for (int i = 0; i < 5; ++i) {
        size_t c = (size_t)cand[i];
        size_t need = fixed
            + (((size_t)SPLIT * c * F1_ * 4 + 255) & ~(size_t)255)   // part
            + ((c * (size_t)L0_ * NCH * 2 + 255) & ~(size_t)255)     // buf0
            + ((c * (size_t)L1_ * NCH * 2 + 255) & ~(size_t)255);    // buf1
        if (need <= ws_size) { CB = cand[i]; break; }
    }
    if (CB == 0) return;
    const int nchunk = B_SZ / CB;

    const size_t o_part = alloc((size_t)SPLIT * CB * F1_ * 4);
    const size_t o_buf0 = alloc((size_t)CB * L0_ * NCH * 2);
    const size_t o_buf1 = alloc((size_t)CB * L1_ * NCH * 2);

    f16*   wpw  = (f16*)(base + o_wpw);
    f16*   wct1 = (f16*)(base + o_wct1);
    f16*   wct2 = (f16*)(base + o_wct2);
    f16*   wct3 = (f16*)(base + o_wct3);
    f16*   wf1h = (f16*)(base + o_wf1h);
    f16*   xh   = (f16*)(base + o_xh);
    float* h4   = (float*)(base + o_h4);
    float* part = (float*)(base + o_part);
    f16*   buf0 = (f16*)(base + o_buf0);
    f16*   buf1 = (f16*)(base + o_buf1);

    // ---- preps ---------------------------------------------------------
    prep_wpw<<<128, 256, 0, stream>>>(Wp, wpw);
    prep_wct3<<<2304, 256, 0, stream>>>(W1, W2, W3, wct1, wct2, wct3);
    prep_wf1k<<<F1_, 256, 0, stream>>>(Wf1, wf1h);
    prep_xh<<<(int)((((size_t)B_SZ * 8192 + 64) / 4 + 255) / 256), 256, 0, stream>>>(x, xh);

    // ---- chunked pipeline ----------------------------------------------
    for (int c = 0; c < nchunk; ++c) {
        const size_t b0 = (size_t)c * CB;
        // pointwise as K=128 GEMM: in = xh[b][(l+1)*64..]; x0 at in-64
        convk<4, 4, 16, 128, 128, 128, L0_, true><<<CB, 512, 0, stream>>>(
            xh + b0 * 8192 + 64, 8192, wpw, bp, buf0);
        convk<24, 8, 32, 256, 130, L0_, L1_, false><<<CB, 512, 0, stream>>>(
            buf0, (long)L0_ * NCH, wct1, b1, buf1);
        convk<24, 8, 32, 256, 130, L1_, L2_, false><<<CB, 512, 0, stream>>>(
            buf1, (long)L1_ * NCH, wct2, b2, buf0);
        convk<24, 8, 32, 256, 130, L2_, L3_, false><<<CB, 512, 0, stream>>>(
            buf0, (long)L2_ * NCH, wct3, b3, buf1);
        // conv3 output [l][co] IS the FC1 A layout (wf1h K-permuted at prep)
        fc1k<<<dim3(CB / 128, 2, SPLIT), 512, 0, stream>>>(buf1, wf1h, part, CB);
        fc1_reduce_kernel<<<CB * F1_ / 1024, 256, 0, stream>>>(part, bf1,
                                                               h4 + b0 * F1_, CB);
    }

    fc2_kernel<<<B_SZ / 4, 256, 0, stream>>>(h4, Wf2, bf2, out);
}